// Round 2
// baseline (20153.912 us; speedup 1.0000x reference)
//
#include <hip/hip_runtime.h>
#include <math.h>

// ---------------- problem constants ----------------
#define S_LEN 2048
#define BATCH 8
#define DIM   512
#define HID   1024

// ---------------- workspace offsets (floats). Peak use ~205 MB ----------------
static const size_t OFF_XIN   = 0;            // 16,777,216  xin (B,S,H); later y (32768x512)
static const size_t OFF_BM    = 16777216;     // 16,777,216  Bm -> ssm states -> ln'd (in place)
static const size_t OFF_RES   = 33554432;     // 16,777,216  res states -> ln'd; later gate (first 8,388,608)
static const size_t OFF_MEAN  = 50331648;     // 16,384
static const size_t OFF_RSTD  = 50348032;     // 16,384
static const size_t OFF_DELTA = 50364416;     // 16,384
static const size_t OFF_AC    = 50380800;     // 262,144
static const size_t OFF_BC    = 50642944;     // 262,144
static const size_t OFF_HST   = 50905088;     // 262,144
static const size_t OFF_HBUF  = 51167232;     // 16,384 (2 x 8 x 1024)
static const size_t OFF_BAR   = 51183616;     // 4096 u32 flags (256 WGs x 16-u32 stride)

// =====================================================================
// K1: per-row LN stats over D=512 (mean, rstd) + delta = softplus(xn.wd + b)
// =====================================================================
__global__ __launch_bounds__(128) void ln_stats_kernel(
    const float* __restrict__ x, const float* __restrict__ g, const float* __restrict__ b,
    const float* __restrict__ wd, const float* __restrict__ bd,
    float* __restrict__ meanO, float* __restrict__ rstdO, float* __restrict__ deltaO)
{
    const int m = blockIdx.x;
    const int tid = threadIdx.x;
    float4 v = ((const float4*)(x + (size_t)m * DIM))[tid];
    float s1 = v.x + v.y + v.z + v.w;
    float s2 = v.x*v.x + v.y*v.y + v.z*v.z + v.w*v.w;
    #pragma unroll
    for (int o = 1; o < 64; o <<= 1) { s1 += __shfl_xor(s1, o); s2 += __shfl_xor(s2, o); }
    __shared__ float sA[4];
    if ((tid & 63) == 0) { sA[tid >> 6] = s1; sA[2 + (tid >> 6)] = s2; }
    __syncthreads();
    s1 = sA[0] + sA[1]; s2 = sA[2] + sA[3];
    const float mean = s1 * (1.0f / DIM);
    const float var  = s2 * (1.0f / DIM) - mean * mean;
    const float rstd = 1.0f / sqrtf(var + 1e-5f);
    float4 gv = ((const float4*)g)[tid];
    float4 bv = ((const float4*)b)[tid];
    float4 wv = ((const float4*)wd)[tid];
    float y0 = (v.x - mean) * rstd * gv.x + bv.x;
    float y1 = (v.y - mean) * rstd * gv.y + bv.y;
    float y2 = (v.z - mean) * rstd * gv.z + bv.z;
    float y3 = (v.w - mean) * rstd * gv.w + bv.w;
    float dd = y0*wv.x + y1*wv.y + y2*wv.z + y3*wv.w;
    #pragma unroll
    for (int o = 1; o < 64; o <<= 1) dd += __shfl_xor(dd, o);
    __shared__ float sB[2];
    if ((tid & 63) == 0) sB[tid >> 6] = dd;
    __syncthreads();
    if (tid == 0) {
        meanO[m] = mean;
        rstdO[m] = rstd;
        float t = sB[0] + sB[1] + bd[0];
        deltaO[m] = fmaxf(t, 0.0f) + log1pf(expf(-fabsf(t)));   // stable softplus
    }
}

// =====================================================================
// SGEMM: C[M,N] = A[M,K] @ Bw[N,K]^T  (128x128 tile, BK=16, 8x8/thread)
// LNA: apply per-row layernorm to A while staging (mean/rstd per row, g/b per col)
// EPI: 0 none | 2 sigmoid(z+bias) | 3 gelu_exact(z+bias)
// =====================================================================
template<int EPI, bool LNA>
__global__ __launch_bounds__(256) void sgemm_bt(
    const float* __restrict__ A, const float* __restrict__ Bw,
    float* __restrict__ C, const float* __restrict__ bias,
    const float* __restrict__ lnMean, const float* __restrict__ lnRstd,
    const float* __restrict__ lnG, const float* __restrict__ lnB,
    int M, int N, int K)
{
    __shared__ __align__(16) float As[16][128];
    __shared__ __align__(16) float Bs[16][128];
    const int tid = threadIdx.x;
    const int tx = tid & 15, ty = tid >> 4;
    const size_t bm = blockIdx.x, bn = blockIdx.y;
    const float* Ab = A  + bm * 128 * (size_t)K;
    const float* Bb = Bw + bn * 128 * (size_t)K;
    const int lr = tid >> 1;          // 0..127 row in tile
    const int lk = (tid & 1) * 8;     // 0 or 8
    float mu = 0.0f, rs = 0.0f;
    if (LNA) { mu = lnMean[bm * 128 + lr]; rs = lnRstd[bm * 128 + lr]; }
    float acc[8][8] = {};
    for (int kt = 0; kt < K; kt += 16) {
        float4 a0 = *(const float4*)(Ab + (size_t)lr * K + kt + lk);
        float4 a1 = *(const float4*)(Ab + (size_t)lr * K + kt + lk + 4);
        float4 b0 = *(const float4*)(Bb + (size_t)lr * K + kt + lk);
        float4 b1 = *(const float4*)(Bb + (size_t)lr * K + kt + lk + 4);
        if (LNA) {
            float4 g0 = *(const float4*)(lnG + kt + lk);
            float4 g1 = *(const float4*)(lnG + kt + lk + 4);
            float4 h0 = *(const float4*)(lnB + kt + lk);
            float4 h1 = *(const float4*)(lnB + kt + lk + 4);
            a0.x = (a0.x - mu) * rs * g0.x + h0.x;  a0.y = (a0.y - mu) * rs * g0.y + h0.y;
            a0.z = (a0.z - mu) * rs * g0.z + h0.z;  a0.w = (a0.w - mu) * rs * g0.w + h0.w;
            a1.x = (a1.x - mu) * rs * g1.x + h1.x;  a1.y = (a1.y - mu) * rs * g1.y + h1.y;
            a1.z = (a1.z - mu) * rs * g1.z + h1.z;  a1.w = (a1.w - mu) * rs * g1.w + h1.w;
        }
        __syncthreads();
        As[lk+0][lr]=a0.x; As[lk+1][lr]=a0.y; As[lk+2][lr]=a0.z; As[lk+3][lr]=a0.w;
        As[lk+4][lr]=a1.x; As[lk+5][lr]=a1.y; As[lk+6][lr]=a1.z; As[lk+7][lr]=a1.w;
        Bs[lk+0][lr]=b0.x; Bs[lk+1][lr]=b0.y; Bs[lk+2][lr]=b0.z; Bs[lk+3][lr]=b0.w;
        Bs[lk+4][lr]=b1.x; Bs[lk+5][lr]=b1.y; Bs[lk+6][lr]=b1.z; Bs[lk+7][lr]=b1.w;
        __syncthreads();
        #pragma unroll
        for (int kk = 0; kk < 16; ++kk) {
            float av[8], bv[8];
            *(float4*)&av[0] = *(const float4*)&As[kk][ty*8];
            *(float4*)&av[4] = *(const float4*)&As[kk][ty*8+4];
            *(float4*)&bv[0] = *(const float4*)&Bs[kk][tx*8];
            *(float4*)&bv[4] = *(const float4*)&Bs[kk][tx*8+4];
            #pragma unroll
            for (int i = 0; i < 8; ++i)
                #pragma unroll
                for (int j = 0; j < 8; ++j)
                    acc[i][j] = fmaf(av[i], bv[j], acc[i][j]);
        }
    }
    const size_t crow = bm * 128 + ty * 8;
    const size_t ccol = bn * 128 + tx * 8;
    float bs8[8];
    if (EPI == 2 || EPI == 3) {
        #pragma unroll
        for (int j = 0; j < 8; ++j) bs8[j] = bias[ccol + j];
    }
    #pragma unroll
    for (int i = 0; i < 8; ++i) {
        #pragma unroll
        for (int j = 0; j < 8; ++j) {
            const size_t idx = (crow + i) * (size_t)N + ccol + j;
            float v = acc[i][j];
            if (EPI == 0) {
                C[idx] = v;
            } else if (EPI == 2) {
                float z = v + bs8[j];
                C[idx] = 1.0f / (1.0f + expf(-z));
            } else {
                float z = v + bs8[j];
                C[idx] = 0.5f * z * (1.0f + erff(z * 0.70710678118654752f));
            }
        }
    }
}

// =====================================================================
// K4: reservoir scan. Regular launch, 256 WGs x 512 thr (all-resident:
// 4KB LDS, ~90 VGPR -> far below any occupancy limit; 256 WGs on 256 CUs).
// Group = batch b = blockIdx&7 (XCD-local under round-robin: perf only).
// W_res slice (32 rows/WG) in REGISTERS; h vector staged in LDS.
// Barrier: per-WG flag lines + wave-parallel poll (no atomic contention);
// __threadfence (agent wb/inv) for cross-XCD correctness.
// =====================================================================
__global__ __launch_bounds__(512) void reservoir_scan(
    const float* __restrict__ xin, const float* __restrict__ Wres,
    float* __restrict__ res, float* __restrict__ hbuf, unsigned int* __restrict__ bar)
{
    __shared__ __align__(16) float hl[HID];
    const int b   = blockIdx.x & 7;
    const int w   = blockIdx.x >> 3;
    const int tid = threadIdx.x;
    const int r   = tid >> 4;        // 0..31 row within WG
    const int l   = tid & 15;        // 0..15 k-lane
    const int row = w * 32 + r;

    // W row slice in registers: cols {i*64 + l*4 .. +3}, i = 0..15 (64 floats)
    float4 wreg[16];
    {
        const float* Wr = Wres + (size_t)row * HID;
        #pragma unroll
        for (int i = 0; i < 16; ++i)
            wreg[i] = *(const float4*)(Wr + i * 64 + l * 4);
    }
    if (tid < 256) ((float4*)hl)[tid] = float4{0.f, 0.f, 0.f, 0.f};
    __syncthreads();

    const float* xb = xin + (size_t)b * S_LEN * HID;
    float*       rb = res + (size_t)b * S_LEN * HID;
    unsigned int* gflags = bar + (size_t)b * 512;        // 32 flags, stride 16 u32
    unsigned int* myflag = gflags + (size_t)w * 16;

    float xv = (l == 0) ? xb[row] : 0.0f;   // xin[t=0][row]

    for (int t = 0; t < S_LEN; ++t) {
        float xnext = (l == 0 && t + 1 < S_LEN) ? xb[(size_t)(t + 1) * HID + row] : 0.0f;

        float acc = 0.0f;
        #pragma unroll
        for (int i = 0; i < 16; ++i) {
            float4 hv = *(const float4*)(hl + i * 64 + l * 4);
            acc = fmaf(wreg[i].x, hv.x, acc);
            acc = fmaf(wreg[i].y, hv.y, acc);
            acc = fmaf(wreg[i].z, hv.z, acc);
            acc = fmaf(wreg[i].w, hv.w, acc);
        }
        #pragma unroll
        for (int o = 1; o < 16; o <<= 1) acc += __shfl_xor(acc, o);

        if (l == 0) {
            float nh = 0.95f * tanhf(xv + acc) + 0.05f * hl[row];
            rb[(size_t)t * HID + row] = nh;
            hbuf[((t + 1) & 1) * (BATCH * HID) + b * HID + row] = nh;
        }
        xv = xnext;

        __syncthreads();   // compiler drains vmcnt before s_barrier: h stores complete
        if (tid == 0) {
            __threadfence();                                   // release (L2 wb to coherent point)
            __hip_atomic_store(myflag, (unsigned int)(t + 1),
                               __ATOMIC_RELAXED, __HIP_MEMORY_SCOPE_AGENT);
        }
        if (tid < 64) {    // wave 0: poll all 32 group flags in parallel
            const unsigned int target = (unsigned int)(t + 1);
            bool done = (tid >= 32);
            while (true) {
                if (!done)
                    done = __hip_atomic_load(gflags + (size_t)tid * 16,
                                             __ATOMIC_RELAXED, __HIP_MEMORY_SCOPE_AGENT) >= target;
                if (__all(done)) break;
                __builtin_amdgcn_s_sleep(1);
            }
            if (tid == 0) __threadfence();                     // acquire (invalidate stale)
        }
        __syncthreads();

        if (t + 1 < S_LEN) {   // stage h_{t+1} into LDS
            if (tid < 256)
                ((float4*)hl)[tid] =
                    ((const float4*)(hbuf + ((t + 1) & 1) * (BATCH * HID) + b * HID))[tid];
            __syncthreads();
        }
    }
}

// =====================================================================
// K5: diagonal SSM scan, 3-pass chunked; A_bar/B_bar computed on the fly
// =====================================================================
__global__ __launch_bounds__(1024) void ssm_chunk(
    const float* __restrict__ Bm, const float* __restrict__ delta,
    const float* __restrict__ Avec, float* __restrict__ Ac, float* __restrict__ Bc)
{
    const int blk = blockIdx.x;              // b*32 + c
    const int b = blk >> 5, c = blk & 31, h = threadIdx.x;
    const float A = Avec[h];
    const float invA = 1.0f / (A + 1e-8f);
    const int m0 = b * S_LEN + c * 64;
    const size_t base = (size_t)m0 * HID + h;
    float ap = 1.0f, acc = 0.0f;
    for (int s = 0; s < 64; ++s) {
        float a  = expf(A * delta[m0 + s]);
        float bb = Bm[base + (size_t)s * HID] * (1.0f - a) * invA;
        acc = a * acc + bb;
        ap *= a;
    }
    Ac[(size_t)blk * HID + h] = ap;
    Bc[(size_t)blk * HID + h] = acc;
}

__global__ __launch_bounds__(1024) void ssm_chain(
    const float* __restrict__ Ac, const float* __restrict__ Bc, float* __restrict__ hst)
{
    const int b = blockIdx.x, h = threadIdx.x;
    float hs = 0.0f;
    for (int c = 0; c < 32; ++c) {
        size_t idx = ((size_t)b * 32 + c) * HID + h;
        hst[idx] = hs;
        hs = Ac[idx] * hs + Bc[idx];
    }
}

__global__ __launch_bounds__(1024) void ssm_expand(
    float* __restrict__ Bm, const float* __restrict__ delta,
    const float* __restrict__ Avec, const float* __restrict__ hst)
{
    const int blk = blockIdx.x;
    const int b = blk >> 5, c = blk & 31, h = threadIdx.x;
    const float A = Avec[h];
    const float invA = 1.0f / (A + 1e-8f);
    const int m0 = b * S_LEN + c * 64;
    const size_t base = (size_t)m0 * HID + h;
    float hv = hst[(size_t)blk * HID + h];
    for (int s = 0; s < 64; ++s) {
        float a  = expf(A * delta[m0 + s]);
        float bb = Bm[base + (size_t)s * HID] * (1.0f - a) * invA;
        hv = a * hv + bb;
        Bm[base + (size_t)s * HID] = hv;    // in-place: read-before-write per element
    }
}

// =====================================================================
// K6: readout LayerNorm over H=1024, in place, stacked 32768 rows
// =====================================================================
__global__ __launch_bounds__(256) void ln_h_kernel(
    float* __restrict__ st, const float* __restrict__ g, const float* __restrict__ bb)
{
    const int m = blockIdx.x, tid = threadIdx.x;
    float* rowp = st + (size_t)m * HID;
    float4 v = ((const float4*)rowp)[tid];
    float s1 = v.x + v.y + v.z + v.w;
    float s2 = v.x*v.x + v.y*v.y + v.z*v.z + v.w*v.w;
    #pragma unroll
    for (int o = 1; o < 64; o <<= 1) { s1 += __shfl_xor(s1, o); s2 += __shfl_xor(s2, o); }
    __shared__ float sh[8];
    if ((tid & 63) == 0) { sh[tid >> 6] = s1; sh[4 + (tid >> 6)] = s2; }
    __syncthreads();
    s1 = sh[0] + sh[1] + sh[2] + sh[3];
    s2 = sh[4] + sh[5] + sh[6] + sh[7];
    const float mean = s1 * (1.0f / HID);
    const float var  = s2 * (1.0f / HID) - mean * mean;
    const float rstd = 1.0f / sqrtf(var + 1e-5f);
    float4 gv = ((const float4*)g)[tid];
    float4 bv = ((const float4*)bb)[tid];
    float4 y;
    y.x = (v.x - mean) * rstd * gv.x + bv.x;
    y.y = (v.y - mean) * rstd * gv.y + bv.y;
    y.z = (v.z - mean) * rstd * gv.z + bv.z;
    y.w = (v.w - mean) * rstd * gv.w + bv.w;
    ((float4*)rowp)[tid] = y;
}

// =====================================================================
// K7: gated fusion. y rows 0..16383 = ssm branch, 16384..32767 = reservoir
// =====================================================================
__global__ __launch_bounds__(256) void fuse_kernel(
    const float* __restrict__ y, const float* __restrict__ gate, float* __restrict__ out)
{
    const int i = blockIdx.x * 256 + threadIdx.x;
    float4 ys = ((const float4*)y)[i];                 // ssm
    float4 yr = ((const float4*)y)[i + 2097152];       // reservoir
    float4 g  = ((const float4*)gate)[i];
    float4 o;
    o.x = yr.x * g.x + ys.x * (1.0f - g.x);
    o.y = yr.y * g.y + ys.y * (1.0f - g.y);
    o.z = yr.z * g.z + ys.z * (1.0f - g.z);
    o.w = yr.w * g.w + ys.w * (1.0f - g.w);
    ((float4*)out)[i] = o;
}

// =====================================================================
extern "C" void kernel_launch(void* const* d_in, const int* in_sizes, int n_in,
                              void* d_out, int out_size, void* d_ws, size_t ws_size,
                              hipStream_t stream)
{
    const float* x       = (const float*)d_in[0];
    const float* norm_g  = (const float*)d_in[1];
    const float* norm_b  = (const float*)d_in[2];
    const float* W_in    = (const float*)d_in[3];
    const float* W_res   = (const float*)d_in[4];
    const float* Avec    = (const float*)d_in[5];
    const float* W_B     = (const float*)d_in[6];
    const float* w_delta = (const float*)d_in[7];
    const float* b_delta = (const float*)d_in[8];
    const float* ro_g    = (const float*)d_in[9];
    const float* ro_b    = (const float*)d_in[10];
    const float* W_ro    = (const float*)d_in[11];
    const float* b_ro    = (const float*)d_in[12];
    const float* W_gate  = (const float*)d_in[13];
    const float* b_gate  = (const float*)d_in[14];
    float* out = (float*)d_out;

    float* W = (float*)d_ws;
    float* xin   = W + OFF_XIN;
    float* Bm    = W + OFF_BM;
    float* resS  = W + OFF_RES;
    float* meanB = W + OFF_MEAN;
    float* rstdB = W + OFF_RSTD;
    float* delta = W + OFF_DELTA;
    float* Ac    = W + OFF_AC;
    float* Bc    = W + OFF_BC;
    float* hst   = W + OFF_HST;
    float* hbuf  = W + OFF_HBUF;
    unsigned int* bar = (unsigned int*)(W + OFF_BAR);
    float* stacked = Bm;            // 32768 x 1024 (Bm then res, contiguous)
    float* ybuf    = W + OFF_XIN;   // 32768 x 512 (xin dead after scan)
    float* gbuf    = W + OFF_RES;   // 16384 x 512 (res dead after readout)

    // 1) LN stats + delta
    ln_stats_kernel<<<16384, 128, 0, stream>>>(x, norm_g, norm_b, w_delta, b_delta,
                                               meanB, rstdB, delta);
    // 2) xin = LN(x) @ W_in^T   (LN fused into A staging)
    sgemm_bt<0, true><<<dim3(128, 8), 256, 0, stream>>>(
        x, W_in, xin, nullptr, meanB, rstdB, norm_g, norm_b, 16384, 1024, 512);
    // 3) Bm = LN(x) @ W_B^T
    sgemm_bt<0, true><<<dim3(128, 8), 256, 0, stream>>>(
        x, W_B, Bm, nullptr, meanB, rstdB, norm_g, norm_b, 16384, 1024, 512);
    // 4) reservoir scan
    (void)hipMemsetAsync(bar, 0, 4096 * sizeof(unsigned int), stream);
    reservoir_scan<<<256, 512, 0, stream>>>(xin, W_res, resS, hbuf, bar);
    // 5) SSM scan (chunked, parallel; A_bar/B_bar on the fly)
    ssm_chunk<<<256, 1024, 0, stream>>>(Bm, delta, Avec, Ac, Bc);
    ssm_chain<<<8, 1024, 0, stream>>>(Ac, Bc, hst);
    ssm_expand<<<256, 1024, 0, stream>>>(Bm, delta, Avec, hst);
    // 6) readout LN in place on stacked [ssm; res] rows
    ln_h_kernel<<<32768, 256, 0, stream>>>(stacked, ro_g, ro_b);
    // 7) y = gelu(stacked_ln @ W_ro^T + b_ro), single M=32768 GEMM into xin slot
    sgemm_bt<3, false><<<dim3(256, 4), 256, 0, stream>>>(
        stacked, W_ro, ybuf, b_ro, nullptr, nullptr, nullptr, nullptr, 32768, 512, 1024);
    // 8) gate = sigmoid(x @ W_gate^T + b_gate) into res slot
    sgemm_bt<2, false><<<dim3(128, 4), 256, 0, stream>>>(
        x, W_gate, gbuf, b_gate, nullptr, nullptr, nullptr, nullptr, 16384, 512, 512);
    // 9) fuse
    fuse_kernel<<<8192, 256, 0, stream>>>(ybuf, gbuf, out);
}

// Round 3
// 5210.925 us; speedup vs baseline: 3.8676x; 3.8676x over previous
//
#include <hip/hip_runtime.h>
#include <math.h>

// ---------------- problem constants ----------------
#define S_LEN 2048
#define BATCH 8
#define DIM   512
#define HID   1024

// ---------------- workspace offsets (floats). Peak use ~205 MB ----------------
static const size_t OFF_XIN   = 0;            // 16,777,216  xin (B,S,H); later y (32768x512)
static const size_t OFF_BM    = 16777216;     // 16,777,216  Bm -> ssm states -> ln'd (in place)
static const size_t OFF_RES   = 33554432;     // 16,777,216  res states -> ln'd; later gate
static const size_t OFF_MEAN  = 50331648;     // 16,384
static const size_t OFF_RSTD  = 50348032;     // 16,384
static const size_t OFF_DELTA = 50364416;     // 16,384
static const size_t OFF_AC    = 50380800;     // 262,144
static const size_t OFF_BC    = 50642944;     // 262,144
static const size_t OFF_HST   = 50905088;     // 262,144
static const size_t OFF_HBUF  = 51167232;     // 16,384 (2 x 8 x 1024)
static const size_t OFF_BAR   = 51183616;     // 8192 u32 flags (8 batches x 32 WGs x 32-u32 stride)

// =====================================================================
// K1: per-row LN stats over D=512 (mean, rstd) + delta = softplus(xn.wd + b)
// =====================================================================
__global__ __launch_bounds__(128) void ln_stats_kernel(
    const float* __restrict__ x, const float* __restrict__ g, const float* __restrict__ b,
    const float* __restrict__ wd, const float* __restrict__ bd,
    float* __restrict__ meanO, float* __restrict__ rstdO, float* __restrict__ deltaO)
{
    const int m = blockIdx.x;
    const int tid = threadIdx.x;
    float4 v = ((const float4*)(x + (size_t)m * DIM))[tid];
    float s1 = v.x + v.y + v.z + v.w;
    float s2 = v.x*v.x + v.y*v.y + v.z*v.z + v.w*v.w;
    #pragma unroll
    for (int o = 1; o < 64; o <<= 1) { s1 += __shfl_xor(s1, o); s2 += __shfl_xor(s2, o); }
    __shared__ float sA[4];
    if ((tid & 63) == 0) { sA[tid >> 6] = s1; sA[2 + (tid >> 6)] = s2; }
    __syncthreads();
    s1 = sA[0] + sA[1]; s2 = sA[2] + sA[3];
    const float mean = s1 * (1.0f / DIM);
    const float var  = s2 * (1.0f / DIM) - mean * mean;
    const float rstd = 1.0f / sqrtf(var + 1e-5f);
    float4 gv = ((const float4*)g)[tid];
    float4 bv = ((const float4*)b)[tid];
    float4 wv = ((const float4*)wd)[tid];
    float y0 = (v.x - mean) * rstd * gv.x + bv.x;
    float y1 = (v.y - mean) * rstd * gv.y + bv.y;
    float y2 = (v.z - mean) * rstd * gv.z + bv.z;
    float y3 = (v.w - mean) * rstd * gv.w + bv.w;
    float dd = y0*wv.x + y1*wv.y + y2*wv.z + y3*wv.w;
    #pragma unroll
    for (int o = 1; o < 64; o <<= 1) dd += __shfl_xor(dd, o);
    __shared__ float sB[2];
    if ((tid & 63) == 0) sB[tid >> 6] = dd;
    __syncthreads();
    if (tid == 0) {
        meanO[m] = mean;
        rstdO[m] = rstd;
        float t = sB[0] + sB[1] + bd[0];
        deltaO[m] = fmaxf(t, 0.0f) + log1pf(expf(-fabsf(t)));   // stable softplus
    }
}

// =====================================================================
// SGEMM: C[M,N] = A[M,K] @ Bw[N,K]^T  (128x128 tile, BK=16, 8x8/thread)
// LNA: apply per-row layernorm to A while staging
// EPI: 0 none | 2 sigmoid(z+bias) | 3 gelu_exact(z+bias)
// =====================================================================
template<int EPI, bool LNA>
__global__ __launch_bounds__(256) void sgemm_bt(
    const float* __restrict__ A, const float* __restrict__ Bw,
    float* __restrict__ C, const float* __restrict__ bias,
    const float* __restrict__ lnMean, const float* __restrict__ lnRstd,
    const float* __restrict__ lnG, const float* __restrict__ lnB,
    int M, int N, int K)
{
    __shared__ __align__(16) float As[16][128];
    __shared__ __align__(16) float Bs[16][128];
    const int tid = threadIdx.x;
    const int tx = tid & 15, ty = tid >> 4;
    const size_t bm = blockIdx.x, bn = blockIdx.y;
    const float* Ab = A  + bm * 128 * (size_t)K;
    const float* Bb = Bw + bn * 128 * (size_t)K;
    const int lr = tid >> 1;          // 0..127 row in tile
    const int lk = (tid & 1) * 8;     // 0 or 8
    float mu = 0.0f, rs = 0.0f;
    if (LNA) { mu = lnMean[bm * 128 + lr]; rs = lnRstd[bm * 128 + lr]; }
    float acc[8][8] = {};
    for (int kt = 0; kt < K; kt += 16) {
        float4 a0 = *(const float4*)(Ab + (size_t)lr * K + kt + lk);
        float4 a1 = *(const float4*)(Ab + (size_t)lr * K + kt + lk + 4);
        float4 b0 = *(const float4*)(Bb + (size_t)lr * K + kt + lk);
        float4 b1 = *(const float4*)(Bb + (size_t)lr * K + kt + lk + 4);
        if (LNA) {
            float4 g0 = *(const float4*)(lnG + kt + lk);
            float4 g1 = *(const float4*)(lnG + kt + lk + 4);
            float4 h0 = *(const float4*)(lnB + kt + lk);
            float4 h1 = *(const float4*)(lnB + kt + lk + 4);
            a0.x = (a0.x - mu) * rs * g0.x + h0.x;  a0.y = (a0.y - mu) * rs * g0.y + h0.y;
            a0.z = (a0.z - mu) * rs * g0.z + h0.z;  a0.w = (a0.w - mu) * rs * g0.w + h0.w;
            a1.x = (a1.x - mu) * rs * g1.x + h1.x;  a1.y = (a1.y - mu) * rs * g1.y + h1.y;
            a1.z = (a1.z - mu) * rs * g1.z + h1.z;  a1.w = (a1.w - mu) * rs * g1.w + h1.w;
        }
        __syncthreads();
        As[lk+0][lr]=a0.x; As[lk+1][lr]=a0.y; As[lk+2][lr]=a0.z; As[lk+3][lr]=a0.w;
        As[lk+4][lr]=a1.x; As[lk+5][lr]=a1.y; As[lk+6][lr]=a1.z; As[lk+7][lr]=a1.w;
        Bs[lk+0][lr]=b0.x; Bs[lk+1][lr]=b0.y; Bs[lk+2][lr]=b0.z; Bs[lk+3][lr]=b0.w;
        Bs[lk+4][lr]=b1.x; Bs[lk+5][lr]=b1.y; Bs[lk+6][lr]=b1.z; Bs[lk+7][lr]=b1.w;
        __syncthreads();
        #pragma unroll
        for (int kk = 0; kk < 16; ++kk) {
            float av[8], bv[8];
            *(float4*)&av[0] = *(const float4*)&As[kk][ty*8];
            *(float4*)&av[4] = *(const float4*)&As[kk][ty*8+4];
            *(float4*)&bv[0] = *(const float4*)&Bs[kk][tx*8];
            *(float4*)&bv[4] = *(const float4*)&Bs[kk][tx*8+4];
            #pragma unroll
            for (int i = 0; i < 8; ++i)
                #pragma unroll
                for (int j = 0; j < 8; ++j)
                    acc[i][j] = fmaf(av[i], bv[j], acc[i][j]);
        }
    }
    const size_t crow = bm * 128 + ty * 8;
    const size_t ccol = bn * 128 + tx * 8;
    float bs8[8];
    if (EPI == 2 || EPI == 3) {
        #pragma unroll
        for (int j = 0; j < 8; ++j) bs8[j] = bias[ccol + j];
    }
    #pragma unroll
    for (int i = 0; i < 8; ++i) {
        #pragma unroll
        for (int j = 0; j < 8; ++j) {
            const size_t idx = (crow + i) * (size_t)N + ccol + j;
            float v = acc[i][j];
            if (EPI == 0) {
                C[idx] = v;
            } else if (EPI == 2) {
                float z = v + bs8[j];
                C[idx] = 1.0f / (1.0f + expf(-z));
            } else {
                float z = v + bs8[j];
                C[idx] = 0.5f * z * (1.0f + erff(z * 0.70710678118654752f));
            }
        }
    }
}

// =====================================================================
// K4: reservoir scan. 256 WGs x 512 thr, group = batch (blockIdx&7).
// W_res slice (32 rows/WG) in registers; h staged in LDS.
// NO FENCES in the loop: all cross-WG data moves via agent-scope
// relaxed atomics (write-through to / read from the coherence point).
// Ordering: per-wave vmcnt(0) drain at __syncthreads guarantees h
// stores are globally visible before tid 0 publishes the step flag.
// =====================================================================
__global__ __launch_bounds__(512) void reservoir_scan(
    const float* __restrict__ xin, const float* __restrict__ Wres,
    float* __restrict__ res, float* __restrict__ hbuf, unsigned int* __restrict__ bar)
{
    __shared__ __align__(16) float hl[HID];
    const int b   = blockIdx.x & 7;
    const int w   = blockIdx.x >> 3;
    const int tid = threadIdx.x;
    const int r   = tid >> 4;        // 0..31 row within WG
    const int l   = tid & 15;        // 0..15 k-lane
    const int row = w * 32 + r;

    // W row slice in registers: cols {i*64 + l*4 .. +3}, i = 0..15 (64 floats)
    float4 wreg[16];
    {
        const float* Wr = Wres + (size_t)row * HID;
        #pragma unroll
        for (int i = 0; i < 16; ++i)
            wreg[i] = *(const float4*)(Wr + i * 64 + l * 4);
    }
    if (tid < 256) ((float4*)hl)[tid] = float4{0.f, 0.f, 0.f, 0.f};
    __syncthreads();

    const float* xb = xin + (size_t)b * S_LEN * HID;
    float*       rb = res + (size_t)b * S_LEN * HID;
    unsigned int* gflags = bar + (size_t)b * 1024;        // 32 flags, stride 32 u32 (128B)
    unsigned int* myflag = gflags + (size_t)w * 32;
    unsigned long long* hb64 = (unsigned long long*)hbuf; // coherent h exchange

    float xv = (l == 0) ? xb[row] : 0.0f;   // xin[t=0][row]

    for (int t = 0; t < S_LEN; ++t) {
        float xnext = (l == 0 && t + 1 < S_LEN) ? xb[(size_t)(t + 1) * HID + row] : 0.0f;

        float acc = 0.0f;
        #pragma unroll
        for (int i = 0; i < 16; ++i) {
            float4 hv = *(const float4*)(hl + i * 64 + l * 4);
            acc = fmaf(wreg[i].x, hv.x, acc);
            acc = fmaf(wreg[i].y, hv.y, acc);
            acc = fmaf(wreg[i].z, hv.z, acc);
            acc = fmaf(wreg[i].w, hv.w, acc);
        }
        #pragma unroll
        for (int o = 1; o < 16; o <<= 1) acc += __shfl_xor(acc, o);

        if (l == 0) {
            float nh = 0.95f * tanhf(xv + acc) + 0.05f * hl[row];
            rb[(size_t)t * HID + row] = nh;
            // write-through to coherence point (no fence needed)
            __hip_atomic_store(
                hbuf + ((t + 1) & 1) * (BATCH * HID) + b * HID + row, nh,
                __ATOMIC_RELAXED, __HIP_MEMORY_SCOPE_AGENT);
        }
        xv = xnext;

        // every wave drains vmcnt before s_barrier => h stores globally visible
        __syncthreads();
        if (tid == 0)
            __hip_atomic_store(myflag, (unsigned int)(t + 1),
                               __ATOMIC_RELAXED, __HIP_MEMORY_SCOPE_AGENT);
        if (tid < 64) {    // wave 0: poll all 32 group flags in parallel (reads LLC)
            const unsigned int target = (unsigned int)(t + 1);
            bool done = (tid >= 32);
            while (true) {
                if (!done)
                    done = __hip_atomic_load(gflags + (size_t)tid * 32,
                                             __ATOMIC_RELAXED, __HIP_MEMORY_SCOPE_AGENT) >= target;
                if (__all(done)) break;
                __builtin_amdgcn_s_sleep(1);
            }
        }
        __syncthreads();

        if (t + 1 < S_LEN) {   // restage h_{t+1}: one u64 agent load per thread
            unsigned long long v = __hip_atomic_load(
                hb64 + ((size_t)((t + 1) & 1)) * (BATCH * HID / 2) + (size_t)b * (HID / 2) + tid,
                __ATOMIC_RELAXED, __HIP_MEMORY_SCOPE_AGENT);
            ((unsigned long long*)hl)[tid] = v;
            __syncthreads();
        }
    }
}

// =====================================================================
// K5: diagonal SSM scan, 3-pass chunked; A_bar/B_bar computed on the fly
// =====================================================================
__global__ __launch_bounds__(1024) void ssm_chunk(
    const float* __restrict__ Bm, const float* __restrict__ delta,
    const float* __restrict__ Avec, float* __restrict__ Ac, float* __restrict__ Bc)
{
    const int blk = blockIdx.x;              // b*32 + c
    const int b = blk >> 5, c = blk & 31, h = threadIdx.x;
    const float A = Avec[h];
    const float invA = 1.0f / (A + 1e-8f);
    const int m0 = b * S_LEN + c * 64;
    const size_t base = (size_t)m0 * HID + h;
    float ap = 1.0f, acc = 0.0f;
    for (int s = 0; s < 64; ++s) {
        float a  = expf(A * delta[m0 + s]);
        float bb = Bm[base + (size_t)s * HID] * (1.0f - a) * invA;
        acc = a * acc + bb;
        ap *= a;
    }
    Ac[(size_t)blk * HID + h] = ap;
    Bc[(size_t)blk * HID + h] = acc;
}

__global__ __launch_bounds__(1024) void ssm_chain(
    const float* __restrict__ Ac, const float* __restrict__ Bc, float* __restrict__ hst)
{
    const int b = blockIdx.x, h = threadIdx.x;
    float hs = 0.0f;
    for (int c = 0; c < 32; ++c) {
        size_t idx = ((size_t)b * 32 + c) * HID + h;
        hst[idx] = hs;
        hs = Ac[idx] * hs + Bc[idx];
    }
}

__global__ __launch_bounds__(1024) void ssm_expand(
    float* __restrict__ Bm, const float* __restrict__ delta,
    const float* __restrict__ Avec, const float* __restrict__ hst)
{
    const int blk = blockIdx.x;
    const int b = blk >> 5, c = blk & 31, h = threadIdx.x;
    const float A = Avec[h];
    const float invA = 1.0f / (A + 1e-8f);
    const int m0 = b * S_LEN + c * 64;
    const size_t base = (size_t)m0 * HID + h;
    float hv = hst[(size_t)blk * HID + h];
    for (int s = 0; s < 64; ++s) {
        float a  = expf(A * delta[m0 + s]);
        float bb = Bm[base + (size_t)s * HID] * (1.0f - a) * invA;
        hv = a * hv + bb;
        Bm[base + (size_t)s * HID] = hv;    // in-place: read-before-write per element
    }
}

// =====================================================================
// K6: readout LayerNorm over H=1024, in place, stacked 32768 rows
// =====================================================================
__global__ __launch_bounds__(256) void ln_h_kernel(
    float* __restrict__ st, const float* __restrict__ g, const float* __restrict__ bb)
{
    const int m = blockIdx.x, tid = threadIdx.x;
    float* rowp = st + (size_t)m * HID;
    float4 v = ((const float4*)rowp)[tid];
    float s1 = v.x + v.y + v.z + v.w;
    float s2 = v.x*v.x + v.y*v.y + v.z*v.z + v.w*v.w;
    #pragma unroll
    for (int o = 1; o < 64; o <<= 1) { s1 += __shfl_xor(s1, o); s2 += __shfl_xor(s2, o); }
    __shared__ float sh[8];
    if ((tid & 63) == 0) { sh[tid >> 6] = s1; sh[4 + (tid >> 6)] = s2; }
    __syncthreads();
    s1 = sh[0] + sh[1] + sh[2] + sh[3];
    s2 = sh[4] + sh[5] + sh[6] + sh[7];
    const float mean = s1 * (1.0f / HID);
    const float var  = s2 * (1.0f / HID) - mean * mean;
    const float rstd = 1.0f / sqrtf(var + 1e-5f);
    float4 gv = ((const float4*)g)[tid];
    float4 bv = ((const float4*)bb)[tid];
    float4 y;
    y.x = (v.x - mean) * rstd * gv.x + bv.x;
    y.y = (v.y - mean) * rstd * gv.y + bv.y;
    y.z = (v.z - mean) * rstd * gv.z + bv.z;
    y.w = (v.w - mean) * rstd * gv.w + bv.w;
    ((float4*)rowp)[tid] = y;
}

// =====================================================================
// K7: gated fusion. y rows 0..16383 = ssm branch, 16384..32767 = reservoir
// =====================================================================
__global__ __launch_bounds__(256) void fuse_kernel(
    const float* __restrict__ y, const float* __restrict__ gate, float* __restrict__ out)
{
    const int i = blockIdx.x * 256 + threadIdx.x;
    float4 ys = ((const float4*)y)[i];                 // ssm
    float4 yr = ((const float4*)y)[i + 2097152];       // reservoir
    float4 g  = ((const float4*)gate)[i];
    float4 o;
    o.x = yr.x * g.x + ys.x * (1.0f - g.x);
    o.y = yr.y * g.y + ys.y * (1.0f - g.y);
    o.z = yr.z * g.z + ys.z * (1.0f - g.z);
    o.w = yr.w * g.w + ys.w * (1.0f - g.w);
    ((float4*)out)[i] = o;
}

// =====================================================================
extern "C" void kernel_launch(void* const* d_in, const int* in_sizes, int n_in,
                              void* d_out, int out_size, void* d_ws, size_t ws_size,
                              hipStream_t stream)
{
    const float* x       = (const float*)d_in[0];
    const float* norm_g  = (const float*)d_in[1];
    const float* norm_b  = (const float*)d_in[2];
    const float* W_in    = (const float*)d_in[3];
    const float* W_res   = (const float*)d_in[4];
    const float* Avec    = (const float*)d_in[5];
    const float* W_B     = (const float*)d_in[6];
    const float* w_delta = (const float*)d_in[7];
    const float* b_delta = (const float*)d_in[8];
    const float* ro_g    = (const float*)d_in[9];
    const float* ro_b    = (const float*)d_in[10];
    const float* W_ro    = (const float*)d_in[11];
    const float* b_ro    = (const float*)d_in[12];
    const float* W_gate  = (const float*)d_in[13];
    const float* b_gate  = (const float*)d_in[14];
    float* out = (float*)d_out;

    float* W = (float*)d_ws;
    float* xin   = W + OFF_XIN;
    float* Bm    = W + OFF_BM;
    float* resS  = W + OFF_RES;
    float* meanB = W + OFF_MEAN;
    float* rstdB = W + OFF_RSTD;
    float* delta = W + OFF_DELTA;
    float* Ac    = W + OFF_AC;
    float* Bc    = W + OFF_BC;
    float* hst   = W + OFF_HST;
    float* hbuf  = W + OFF_HBUF;
    unsigned int* bar = (unsigned int*)(W + OFF_BAR);
    float* stacked = Bm;            // 32768 x 1024 (Bm then res, contiguous)
    float* ybuf    = W + OFF_XIN;   // 32768 x 512 (xin dead after scan)
    float* gbuf    = W + OFF_RES;   // 16384 x 512 (res dead after readout)

    // 1) LN stats + delta
    ln_stats_kernel<<<16384, 128, 0, stream>>>(x, norm_g, norm_b, w_delta, b_delta,
                                               meanB, rstdB, delta);
    // 2) xin = LN(x) @ W_in^T   (LN fused into A staging)
    sgemm_bt<0, true><<<dim3(128, 8), 256, 0, stream>>>(
        x, W_in, xin, nullptr, meanB, rstdB, norm_g, norm_b, 16384, 1024, 512);
    // 3) Bm = LN(x) @ W_B^T
    sgemm_bt<0, true><<<dim3(128, 8), 256, 0, stream>>>(
        x, W_B, Bm, nullptr, meanB, rstdB, norm_g, norm_b, 16384, 1024, 512);
    // 4) reservoir scan
    (void)hipMemsetAsync(bar, 0, 8192 * sizeof(unsigned int), stream);
    reservoir_scan<<<256, 512, 0, stream>>>(xin, W_res, resS, hbuf, bar);
    // 5) SSM scan (chunked, parallel; A_bar/B_bar on the fly)
    ssm_chunk<<<256, 1024, 0, stream>>>(Bm, delta, Avec, Ac, Bc);
    ssm_chain<<<8, 1024, 0, stream>>>(Ac, Bc, hst);
    ssm_expand<<<256, 1024, 0, stream>>>(Bm, delta, Avec, hst);
    // 6) readout LN in place on stacked [ssm; res] rows
    ln_h_kernel<<<32768, 256, 0, stream>>>(stacked, ro_g, ro_b);
    // 7) y = gelu(stacked_ln @ W_ro^T + b_ro), single M=32768 GEMM into xin slot
    sgemm_bt<3, false><<<dim3(256, 4), 256, 0, stream>>>(
        stacked, W_ro, ybuf, b_ro, nullptr, nullptr, nullptr, nullptr, 32768, 512, 1024);
    // 8) gate = sigmoid(x @ W_gate^T + b_gate) into res slot
    sgemm_bt<2, false><<<dim3(128, 4), 256, 0, stream>>>(
        x, W_gate, gbuf, b_gate, nullptr, nullptr, nullptr, nullptr, 16384, 512, 512);
    // 9) fuse
    fuse_kernel<<<8192, 256, 0, stream>>>(ybuf, gbuf, out);
}